// Round 2
// baseline (65.340 us; speedup 1.0000x reference)
//
#include <hip/hip_runtime.h>

// Shapes fixed by the reference.
#define NB    128   // batch
#define NT    128   // LEN_T
#define NA    64    // LEN_A
#define NV    64    // LEN_V

// One block per batch b, one thread per t.
// Math: s_b = dot(V[b], Wv);  y[b,t] = relu( sum_a relu(T[b,t]*A[b,a]*s_b + bv)*Wa[a] + ba )
__global__ __launch_bounds__(NT) void triple_interaction_kernel(
    const float* __restrict__ T,
    const float* __restrict__ A,
    const float* __restrict__ V,
    const float* __restrict__ Wv,
    const float* __restrict__ bv,
    const float* __restrict__ Wa,
    const float* __restrict__ ba,
    float* __restrict__ out)
{
    __shared__ float cf[NA];   // A[b,a] * s_b
    __shared__ float wf[NA];   // Wa[a]
    __shared__ float sS;       // s_b broadcast

    const int b = blockIdx.x;
    const int t = threadIdx.x;

    // --- step 1: s_b = dot(V[b], Wv), computed by wave 0 (lanes 0..63) ---
    if (t < 64) {
        float p = V[b * NV + t] * Wv[t];
        #pragma unroll
        for (int off = 32; off >= 1; off >>= 1)
            p += __shfl_xor(p, off, 64);
        if (t == 0) sS = p;
    }
    __syncthreads();
    const float s = sS;

    // --- step 2: stage per-a coefficients in LDS ---
    if (t < NA) {
        cf[t] = A[b * NA + t] * s;
        wf[t] = Wa[t];
    }
    __syncthreads();

    // --- step 3: per-t contraction over a ---
    const float bvf = bv[0];
    const float baf = ba[0];
    const float tb  = T[b * NT + t];

    float y = 0.0f;
    #pragma unroll
    for (int a = 0; a < NA; ++a) {
        float x = fmaf(tb, cf[a], bvf);   // T*A*s + bv
        x = fmaxf(x, 0.0f);               // relu
        y = fmaf(x, wf[a], y);            // * Wa, accumulate
    }
    y = fmaxf(y + baf, 0.0f);             // + ba, final relu

    out[b * NT + t] = y;
}

extern "C" void kernel_launch(void* const* d_in, const int* in_sizes, int n_in,
                              void* d_out, int out_size, void* d_ws, size_t ws_size,
                              hipStream_t stream) {
    (void)in_sizes; (void)n_in; (void)d_ws; (void)ws_size; (void)out_size;

    const float* T  = (const float*)d_in[0];
    const float* A  = (const float*)d_in[1];
    const float* V  = (const float*)d_in[2];
    const float* Wv = (const float*)d_in[3];
    const float* bv = (const float*)d_in[4];
    const float* Wa = (const float*)d_in[5];
    const float* ba = (const float*)d_in[6];
    float* out = (float*)d_out;

    triple_interaction_kernel<<<NB, NT, 0, stream>>>(T, A, V, Wv, bv, Wa, ba, out);
}